// Round 2
// baseline (8167.113 us; speedup 1.0000x reference)
//
#include <hip/hip_runtime.h>

// WTConv2d fused: DWT -> {dw1,dw3,dw5} -> 1x1 proj -> IDWT, all in one kernel.
// x: [8,128,256,256] f32; w1:[512,1,1,1]; w3:[512,1,3,3]; w5:[512,1,5,5];
// w_proj:[512,1536,1,1]; out: [8,128,256,256] f32.
//
// Block tile: one (b, half-res row i, 128-output-channel group ot).
// K-loop over 512 xd channels; per iter: stage 5x132 x-window (stride-2 reads),
// compute f1/f3/f5 for the 128-pixel row, rank-3 outer-product into
// 8x8 fp32 acc per thread (block tile 128 o x 128 j).

constexpr int CC = 128;          // base channels
constexpr int HH = 256, WW = 256;
constexpr int H2 = 128, W2 = 128;
constexpr int C4 = 512;          // 4*C
constexpr int K12 = 1536;        // 12*C

__global__ __launch_bounds__(256)
void wtconv_fused(const float* __restrict__ x,
                  const float* __restrict__ w1,
                  const float* __restrict__ w3,
                  const float* __restrict__ w5,
                  const float* __restrict__ wp,
                  float* __restrict__ out)
{
    __shared__ float lx[5][136];   // xd rows i-2..i+2, cols -2..129 (132 used)
    __shared__ float lf[3][128];   // f1, f3, f5 for the row
    __shared__ float lwp[3][128];  // proj weights for this o-tile, this c4

    const int tid = threadIdx.x;
    const int i  = blockIdx.x;     // 0..127  half-res row
    const int b  = blockIdx.y;     // 0..7
    const int ot = blockIdx.z;     // 0..3 -> output channels ot*128 .. +127
    const int to = tid & 15;       // o-subgroup: o = ot*128 + to*8 + oo
    const int tj = tid >> 4;       // j-subgroup: j = tj*8 + jj

    float acc[8][8];
#pragma unroll
    for (int a = 0; a < 8; ++a)
#pragma unroll
        for (int c = 0; c < 8; ++c) acc[a][c] = 0.f;

    for (int c4 = 0; c4 < C4; ++c4) {
        const int bc = c4 & 127;       // base channel in x
        const int q  = c4 >> 7;        // DWT quadrant
        const int qy = q >> 1, qx = q & 1;
        const float* xbase = x + (size_t)(b * CC + bc) * (HH * WW);

        // ---- stage xd window (5 rows x 132 cols), zero-padded ----
        for (int e = tid; e < 5 * 132; e += 256) {
            int r  = e / 132;
            int cj = e - r * 132;
            int ri = i + r - 2;        // half-res row index
            int rj = cj - 2;           // half-res col index
            float v = 0.f;
            if ((unsigned)ri < (unsigned)H2 && (unsigned)rj < (unsigned)W2)
                v = xbase[(2 * ri + qy) * WW + (2 * rj + qx)];
            lx[r][cj] = v;
        }
        // ---- stage projection weights (384 entries, 256 threads: strided) ----
        for (int e = tid; e < 384; e += 256) {
            int g = e >> 7, oo = e & 127;
            lwp[g][oo] = wp[(size_t)(ot * 128 + oo) * K12 + g * C4 + c4];
        }
        __syncthreads();

        // ---- depthwise convs for the 128-pixel row ----
        for (int e = tid; e < 384; e += 256) {
            int g = e >> 7, px = e & 127;
            float f = 0.f;
            if (g == 0) {
                f = w1[c4] * lx[2][px + 2];
            } else if (g == 1) {
#pragma unroll
                for (int u = 0; u < 3; ++u)
#pragma unroll
                    for (int v = 0; v < 3; ++v)
                        f += w3[c4 * 9 + u * 3 + v] * lx[1 + u][px + 1 + v];
            } else {
#pragma unroll
                for (int u = 0; u < 5; ++u)
#pragma unroll
                    for (int v = 0; v < 5; ++v)
                        f += w5[c4 * 25 + u * 5 + v] * lx[u][px + v];
            }
            lf[g][px] = f;
        }
        __syncthreads();

        // ---- rank-3 outer product into accumulators ----
        float F1[8], F3[8], F5[8], WA[8], WB[8], WC[8];
#pragma unroll
        for (int jj = 0; jj < 8; ++jj) {
            F1[jj] = lf[0][tj * 8 + jj];
            F3[jj] = lf[1][tj * 8 + jj];
            F5[jj] = lf[2][tj * 8 + jj];
        }
#pragma unroll
        for (int oo = 0; oo < 8; ++oo) {
            WA[oo] = lwp[0][to * 8 + oo];
            WB[oo] = lwp[1][to * 8 + oo];
            WC[oo] = lwp[2][to * 8 + oo];
        }
#pragma unroll
        for (int oo = 0; oo < 8; ++oo)
#pragma unroll
            for (int jj = 0; jj < 8; ++jj)
                acc[oo][jj] += WA[oo] * F1[jj] + WB[oo] * F3[jj] + WC[oo] * F5[jj];
        __syncthreads();   // protect lx/lf/lwp for next c4
    }

    // ---- IDWT scatter write: q_out = ot (since o = ot*128 + bco) ----
    const int oy = 2 * i + (ot >> 1);
    const int ox = ot & 1;
#pragma unroll
    for (int oo = 0; oo < 8; ++oo) {
        int bco = to * 8 + oo;
        float* obase = out + ((size_t)(b * CC + bco) * HH + oy) * WW;
#pragma unroll
        for (int jj = 0; jj < 8; ++jj) {
            int j = tj * 8 + jj;
            obase[2 * j + ox] = acc[oo][jj];
        }
    }
}

extern "C" void kernel_launch(void* const* d_in, const int* in_sizes, int n_in,
                              void* d_out, int out_size, void* d_ws, size_t ws_size,
                              hipStream_t stream) {
    const float* x  = (const float*)d_in[0];
    const float* w1 = (const float*)d_in[1];
    const float* w3 = (const float*)d_in[2];
    const float* w5 = (const float*)d_in[3];
    const float* wp = (const float*)d_in[4];
    float* out = (float*)d_out;

    dim3 grid(H2, 8, 4);   // (i, b, o-tile)
    dim3 block(256);
    hipLaunchKernelGGL(wtconv_fused, grid, block, 0, stream,
                       x, w1, w3, w5, wp, out);
}

// Round 3
// 1571.717 us; speedup vs baseline: 5.1963x; 5.1963x over previous
//
#include <hip/hip_runtime.h>
#include <hip/hip_bf16.h>

typedef __bf16 bf16_t;
typedef __bf16 bf16x8 __attribute__((ext_vector_type(8)));
typedef float f32x4 __attribute__((ext_vector_type(4)));

constexpr int CC = 128, HH = 256, WW = 256, H2 = 128;
constexpr int C4 = 512, K12 = 1536;

// ---- pre-pass: wp fp32 [512][1536] -> ws bf16 tiled awp[g][cb][o][kk] ----
__global__ __launch_bounds__(512)
void prep_wp(const float* __restrict__ wp, bf16_t* __restrict__ awp) {
    int t = blockIdx.x * 512 + threadIdx.x;        // 0 .. 786431
    int kk = t & 31;
    int o  = (t >> 5) & 511;
    int t2 = t >> 14;                              // g*16 + cb
    int g  = t2 >> 4, cb = t2 & 15;
    awp[t] = (bf16_t)wp[o * K12 + g * C4 + cb * 32 + kk];
}

// ---- fused main: DWT -> dwconvs -> bf16 MFMA proj -> IDWT ----
__global__ __launch_bounds__(512, 2)
void wtconv_mfma(const float* __restrict__ x,
                 const float* __restrict__ w1,
                 const float* __restrict__ w3,
                 const float* __restrict__ w5,
                 const bf16_t* __restrict__ awp,
                 float* __restrict__ out)
{
    __shared__ __align__(16) float  lx[16][5][136];   // x windows, fp32
    __shared__ __align__(16) bf16_t Bt[128][136];     // feats^T [px][k(96)]
    __shared__ __align__(16) bf16_t Al[512 * 32];     // A tile [o][kk], XOR-swizzled
    __shared__ __align__(16) float  lw[32][36];       // conv weights per 32-c4 iter

    const int tid = threadIdx.x;
    // XCD swizzle: each XCD owns one batch, i ascending
    const int n = blockIdx.x;               // 0..1023
    const int m = (n & 7) * 128 + (n >> 3);
    const int b = m >> 7;                   // 0..7
    const int i = m & 127;                  // half-res row

    const int wave = tid >> 6, lane = tid & 63;
    const int wm = wave & 3, wn = wave >> 2;       // 4 M-waves x 2 N-waves
    const int lrow = lane & 15, lkh = lane >> 4;   // frag row / k-half

    f32x4 acc[8][4];
#pragma unroll
    for (int a = 0; a < 8; ++a)
#pragma unroll
        for (int c = 0; c < 4; ++c) acc[a][c] = (f32x4){0.f, 0.f, 0.f, 0.f};

    for (int cb = 0; cb < 16; ++cb) {
        // ---- stage conv weights for c4 in [cb*32, cb*32+32) ----
        for (int e = tid; e < 32 * 35; e += 512) {
            int c4i = e / 35, j = e - c4i * 35;
            int c4g = cb * 32 + c4i;
            float v;
            if (j < 25)      v = w5[c4g * 25 + j];
            else if (j < 34) v = w3[c4g * 9 + (j - 25)];
            else             v = w1[c4g];
            lw[c4i][j] = v;
        }

        for (int half = 0; half < 2; ++half) {
            const int c4base = cb * 32 + half * 16;
            // ---- stage x windows: 16 chan x 5 rows x 132 cols (fp32) ----
            for (int e = tid; e < 16 * 5 * 132; e += 512) {
                int chan = e / 660;
                int rem  = e - chan * 660;
                int r    = rem / 132;
                int col  = rem - r * 132;
                int c4 = c4base + chan;
                int bc = c4 & 127, q = c4 >> 7;
                int qy = q >> 1, qx = q & 1;
                int ri = i + r - 2, rj = col - 2;
                float v = 0.f;
                if ((unsigned)ri < (unsigned)H2 && (unsigned)rj < (unsigned)H2)
                    v = x[(size_t)(b * CC + bc) * (HH * WW)
                          + (2 * ri + qy) * WW + (2 * rj + qx)];
                lx[chan][r][col] = v;
            }
            __syncthreads();

            // ---- depthwise convs: thread = (px, 4 channels) ----
            {
                const int px = tid & 127;
                const int cq = tid >> 7;     // wave-uniform
#pragma unroll
                for (int cc = 0; cc < 4; ++cc) {
                    const int c4loc = cq * 4 + cc;
                    float tap[5][5];
#pragma unroll
                    for (int u = 0; u < 5; ++u)
#pragma unroll
                        for (int v = 0; v < 5; ++v)
                            tap[u][v] = lx[c4loc][u][px + v];
                    const float* w = lw[half * 16 + c4loc];
                    float f5 = 0.f, f3 = 0.f;
#pragma unroll
                    for (int u = 0; u < 5; ++u)
#pragma unroll
                        for (int v = 0; v < 5; ++v)
                            f5 += w[u * 5 + v] * tap[u][v];
#pragma unroll
                    for (int u = 0; u < 3; ++u)
#pragma unroll
                        for (int v = 0; v < 3; ++v)
                            f3 += w[25 + u * 3 + v] * tap[u + 1][v + 1];
                    float f1 = w[34] * tap[2][2];
                    const int col = half * 16 + c4loc;
                    Bt[px][col]      = (bf16_t)f1;
                    Bt[px][32 + col] = (bf16_t)f3;
                    Bt[px][64 + col] = (bf16_t)f5;
                }
            }
            __syncthreads();
        }

        // ---- GEMM: 3 g-phases, K=32 each ----
#pragma unroll 1
        for (int g = 0; g < 3; ++g) {
            // stage A_g: thread tid == o, 64B contiguous, XOR chunk swizzle
            {
                const uint4* s4 = (const uint4*)(awp + (((size_t)(g * 16 + cb) * 512 + tid) << 5));
#pragma unroll
                for (int j = 0; j < 4; ++j) {
                    uint4 d = s4[j];
                    int chunk = j ^ ((tid >> 1) & 3);
                    *(uint4*)&Al[tid * 32 + chunk * 8] = d;
                }
            }
            __syncthreads();

            bf16x8 bfrag[4];
#pragma unroll
            for (int nf = 0; nf < 4; ++nf) {
                int p = wn * 64 + nf * 16 + lrow;
                bfrag[nf] = *(const bf16x8*)&Bt[p][g * 32 + lkh * 8];
            }
#pragma unroll
            for (int mf = 0; mf < 8; ++mf) {
                int o = wm * 128 + mf * 16 + lrow;
                bf16x8 af = *(const bf16x8*)&Al[o * 32 + ((lkh ^ ((o >> 1) & 3)) * 8)];
#pragma unroll
                for (int nf = 0; nf < 4; ++nf)
                    acc[mf][nf] = __builtin_amdgcn_mfma_f32_16x16x32_bf16(
                        af, bfrag[nf], acc[mf][nf], 0, 0, 0);
            }
            __syncthreads();
        }
    }

    // ---- IDWT scatter epilogue: o-quadrant == wm ----
    const int oy = 2 * i + (wm >> 1);
    const int ox = wm & 1;
#pragma unroll
    for (int mf = 0; mf < 8; ++mf)
#pragma unroll
        for (int nf = 0; nf < 4; ++nf)
#pragma unroll
            for (int r = 0; r < 4; ++r) {
                int o   = wm * 128 + mf * 16 + lkh * 4 + r;
                int px  = wn * 64 + nf * 16 + lrow;
                int bco = o & 127;
                out[((size_t)(b * CC + bco) * HH + oy) * WW + 2 * px + ox]
                    = acc[mf][nf][r];
            }
}

extern "C" void kernel_launch(void* const* d_in, const int* in_sizes, int n_in,
                              void* d_out, int out_size, void* d_ws, size_t ws_size,
                              hipStream_t stream) {
    const float* x  = (const float*)d_in[0];
    const float* w1 = (const float*)d_in[1];
    const float* w3 = (const float*)d_in[2];
    const float* w5 = (const float*)d_in[3];
    const float* wp = (const float*)d_in[4];
    float* out = (float*)d_out;
    bf16_t* awp = (bf16_t*)d_ws;            // 786432 bf16 = 1.5 MB

    hipLaunchKernelGGL(prep_wp, dim3(1536), dim3(512), 0, stream, wp, awp);
    hipLaunchKernelGGL(wtconv_mfma, dim3(1024), dim3(512), 0, stream,
                       x, w1, w3, w5, awp, out);
}

// Round 4
// 784.982 us; speedup vs baseline: 10.4042x; 2.0022x over previous
//
#include <hip/hip_runtime.h>
#include <hip/hip_bf16.h>
#include <stdint.h>

typedef __bf16 bf16_t;
typedef __bf16 bf16x8 __attribute__((ext_vector_type(8)));
typedef float f32x4 __attribute__((ext_vector_type(4)));

constexpr int CC = 128, HH = 256, WW = 256;
constexpr int C4 = 512, K12 = 1536;
constexpr int AWP_ELEMS = 786432;           // 512 o x 1536 k bf16, tiled

// ---- prep: pack w_proj -> bf16 tiled [g*16+cb][o][32k]; conv w -> [512][36] f32 ----
__global__ __launch_bounds__(256)
void prep(const float* __restrict__ wp, const float* __restrict__ w1,
          const float* __restrict__ w3, const float* __restrict__ w5,
          bf16_t* __restrict__ awp, float* __restrict__ lwall)
{
    int t = blockIdx.x * 256 + threadIdx.x;
    if (t < AWP_ELEMS) {
        int kk = t & 31, o = (t >> 5) & 511, t2 = t >> 14;
        int g = t2 >> 4, cb = t2 & 15;
        awp[t] = (bf16_t)wp[o * K12 + g * C4 + cb * 32 + kk];
    }
    int u = t - AWP_ELEMS;
    if (u >= 0 && u < 512 * 36) {
        int c4 = u / 36, j = u - c4 * 36;
        float v = 0.f;
        if (j < 25)      v = w5[c4 * 25 + j];
        else if (j < 34) v = w3[c4 * 9 + (j - 25)];
        else if (j == 34) v = w1[c4];
        lwall[u] = v;
    }
}

__device__ __forceinline__ void gload4(const float* g, float* l) {
    __builtin_amdgcn_global_load_lds(
        (const __attribute__((address_space(1))) uint32_t*)g,
        (__attribute__((address_space(3))) uint32_t*)l, 4, 0, 0);
}

// ---- fused main ----
__global__ __launch_bounds__(512, 2)
void wtconv_mfma(const float* __restrict__ x,
                 const bf16_t* __restrict__ awp,
                 const float* __restrict__ lwall,
                 float* __restrict__ out)
{
    __shared__ __align__(16) float  lx[32][5][136];  // 87,040 B; borders stay 0
    __shared__ __align__(16) bf16_t Bt[128][104];    // 26,624 B feats^T [px][96k]
    __shared__ __align__(16) float  lw[2][32][36];   //  9,216 B conv weights pingpong

    const int tid = threadIdx.x;
    const int nb = blockIdx.x;                 // XCD swizzle: XCD owns one batch
    const int m = (nb & 7) * 128 + (nb >> 3);
    const int b = m >> 7, i = m & 127;
    const int wave = tid >> 6, lane = tid & 63;
    const int wm = wave & 3, wn = wave >> 2;   // 4 M-waves x 2 N-waves
    const int lrow = lane & 15, lkh = lane >> 4;
    const float* xb = x + (size_t)b * CC * HH * WW;

    // zero all of lx once (pad cols 0,1,130,131 + OOB rows never reloaded)
    for (int e = tid; e < 32 * 5 * 136 / 4; e += 512)
        ((f32x4*)lx)[e] = (f32x4){0.f, 0.f, 0.f, 0.f};
    __syncthreads();   // lgkm drain: zeros land before any global_load_lds

    f32x4 acc[8][4];
#pragma unroll
    for (int a = 0; a < 8; ++a)
#pragma unroll
        for (int c = 0; c < 4; ++c) acc[a][c] = (f32x4){0.f, 0.f, 0.f, 0.f};

    // ---- async issue of x window for chan-block cb (320 chunks of 64 lanes) ----
    auto issue_lx = [&](int cb) {
        const int q4 = cb >> 2;                 // quadrant (uniform in cb)
        const int qy = q4 >> 1, qx = q4 & 1;
        const int bcb = (cb & 3) * 32;          // base channel
#pragma unroll 1
        for (int t = 0; t < 40; ++t) {
            int q = wave * 40 + t;
            int chan = (q * 6554) >> 16;        // q/10
            int rem = q - chan * 10;
            int r = rem >> 1, h = rem & 1;
            int ri = i + r - 2;
            if ((unsigned)ri < 128u) {
                const float* src = xb + (size_t)(bcb + chan) * (HH * WW)
                                 + (2 * ri + qy) * WW + 2 * (h * 64 + lane) + qx;
                gload4(src, &lx[chan][r][2 + h * 64]);
            }
        }
    };
    auto issue_lw = [&](int cb, int buf) {
        const float* src = lwall + cb * (32 * 36);
        float* dst = &lw[buf][0][0];
#pragma unroll 1
        for (int t = wave; t < 18; t += 8)
            gload4(src + t * 64 + lane, dst + t * 64);
    };

    issue_lw(0, 0);
    issue_lx(0);

    const int pxq = tid & 31, ci = tid >> 5;
    const int px0 = pxq * 4;

#pragma unroll 1
    for (int cb = 0; cb < 16; ++cb) {
        __syncthreads();   // drains vmcnt(0): lx(cb)/lw ready; fences Bt after GEMM(cb-1)

        // ---- depthwise convs: thread = (px-quad, chan ci & ci+16) ----
        const int buf = cb & 1;
#pragma unroll
        for (int cc = 0; cc < 2; ++cc) {
            const int chan = ci + cc * 16;
            f32x4 wv[9];
#pragma unroll
            for (int t = 0; t < 9; ++t)
                wv[t] = *(const f32x4*)&lw[buf][chan][t * 4];
#define WT(idx) (wv[(idx) >> 2][(idx) & 3])
            float f5[4] = {0.f, 0.f, 0.f, 0.f}, f3[4] = {0.f, 0.f, 0.f, 0.f}, f1[4];
#pragma unroll
            for (int r = 0; r < 5; ++r) {
                f32x4 a = *(const f32x4*)&lx[chan][r][px0];
                f32x4 bv = *(const f32x4*)&lx[chan][r][px0 + 4];
                float col[8] = {a[0], a[1], a[2], a[3], bv[0], bv[1], bv[2], bv[3]};
#pragma unroll
                for (int d = 0; d < 4; ++d)
#pragma unroll
                    for (int v = 0; v < 5; ++v)
                        f5[d] += WT(r * 5 + v) * col[d + v];
                if (r >= 1 && r <= 3) {
#pragma unroll
                    for (int d = 0; d < 4; ++d)
#pragma unroll
                        for (int v = 0; v < 3; ++v)
                            f3[d] += WT(25 + (r - 1) * 3 + v) * col[d + 1 + v];
                }
                if (r == 2) {
#pragma unroll
                    for (int d = 0; d < 4; ++d)
                        f1[d] = WT(34) * col[d + 2];
                }
            }
#undef WT
#pragma unroll
            for (int d = 0; d < 4; ++d) {
                Bt[px0 + d][chan]      = (bf16_t)f1[d];
                Bt[px0 + d][32 + chan] = (bf16_t)f3[d];
                Bt[px0 + d][64 + chan] = (bf16_t)f5[d];
            }
        }
        __syncthreads();   // Bt(cb) ready; all waves done reading lx(cb)

        // ---- prefetch next tile (latency hidden under GEMM) ----
        if (cb < 15) { issue_lw(cb + 1, (cb + 1) & 1); issue_lx(cb + 1); }

        // ---- GEMM: B from LDS, A direct from L2-resident awp; no barriers ----
#pragma unroll 1
        for (int g = 0; g < 3; ++g) {
            bf16x8 bfrag[4];
#pragma unroll
            for (int nf = 0; nf < 4; ++nf)
                bfrag[nf] = *(const bf16x8*)&Bt[wn * 64 + nf * 16 + lrow][g * 32 + lkh * 8];
            const bf16_t* abase = awp + (size_t)(g * 16 + cb) * (512 * 32);
#pragma unroll
            for (int mf = 0; mf < 8; ++mf) {
                const int o = wm * 128 + mf * 16 + lrow;
                bf16x8 af = *(const bf16x8*)(abase + o * 32 + lkh * 8);
#pragma unroll
                for (int nf = 0; nf < 4; ++nf)
                    acc[mf][nf] = __builtin_amdgcn_mfma_f32_16x16x32_bf16(
                        af, bfrag[nf], acc[mf][nf], 0, 0, 0);
            }
        }
    }

    // ---- IDWT scatter epilogue: o-quadrant == wm ----
    const int oy = 2 * i + (wm >> 1);
    const int ox = wm & 1;
#pragma unroll
    for (int mf = 0; mf < 8; ++mf)
#pragma unroll
        for (int nf = 0; nf < 4; ++nf)
#pragma unroll
            for (int r = 0; r < 4; ++r) {
                int o  = wm * 128 + mf * 16 + lkh * 4 + r;
                int px = wn * 64 + nf * 16 + lrow;
                int bco = o & 127;
                out[((size_t)(b * CC + bco) * HH + oy) * WW + 2 * px + ox]
                    = acc[mf][nf][r];
            }
}

extern "C" void kernel_launch(void* const* d_in, const int* in_sizes, int n_in,
                              void* d_out, int out_size, void* d_ws, size_t ws_size,
                              hipStream_t stream) {
    const float* x  = (const float*)d_in[0];
    const float* w1 = (const float*)d_in[1];
    const float* w3 = (const float*)d_in[2];
    const float* w5 = (const float*)d_in[3];
    const float* wp = (const float*)d_in[4];
    float* out = (float*)d_out;
    bf16_t* awp  = (bf16_t*)d_ws;                                  // 1.50 MB
    float* lwall = (float*)((char*)d_ws + (size_t)AWP_ELEMS * 2);  // 72 KB

    int prep_total = AWP_ELEMS + 512 * 36;
    hipLaunchKernelGGL(prep, dim3((prep_total + 255) / 256), dim3(256), 0, stream,
                       wp, w1, w3, w5, awp, lwall);
    hipLaunchKernelGGL(wtconv_mfma, dim3(1024), dim3(512), 0, stream,
                       x, awp, lwall, out);
}

// Round 5
// 635.225 us; speedup vs baseline: 12.8570x; 1.2358x over previous
//
#include <hip/hip_runtime.h>
#include <hip/hip_bf16.h>
#include <stdint.h>

typedef __bf16 bf16_t;
typedef __bf16 bf16x8 __attribute__((ext_vector_type(8)));
typedef float f32x4 __attribute__((ext_vector_type(4)));

constexpr int CC = 128, HH = 256, WW = 256;
constexpr int C4 = 512, K12 = 1536;
constexpr int AWP_ELEMS = 786432;           // 512 o x 1536 k bf16, tiled

// ---- prep: pack w_proj -> bf16 tiled [g*16+cb][o][32k]; conv w -> [512][36] f32 ----
__global__ __launch_bounds__(256)
void prep(const float* __restrict__ wp, const float* __restrict__ w1,
          const float* __restrict__ w3, const float* __restrict__ w5,
          bf16_t* __restrict__ awp, float* __restrict__ lwall)
{
    int t = blockIdx.x * 256 + threadIdx.x;
    if (t < AWP_ELEMS) {
        int kk = t & 31, o = (t >> 5) & 511, t2 = t >> 14;
        int g = t2 >> 4, cb = t2 & 15;
        awp[t] = (bf16_t)wp[o * K12 + g * C4 + cb * 32 + kk];
    }
    int u = t - AWP_ELEMS;
    if (u >= 0 && u < 512 * 36) {
        int c4 = u / 36, j = u - c4 * 36;
        float v = 0.f;
        if (j < 25)      v = w5[c4 * 25 + j];
        else if (j < 34) v = w3[c4 * 9 + (j - 25)];
        else if (j == 34) v = w1[c4];
        lwall[u] = v;
    }
}

__device__ __forceinline__ void gload4(const float* g, float* l) {
    __builtin_amdgcn_global_load_lds(
        (const __attribute__((address_space(1))) uint32_t*)g,
        (__attribute__((address_space(3))) uint32_t*)l, 4, 0, 0);
}

__device__ __forceinline__ uint32_t pk_bf16(float a, float b) {
    bf16_t x = (bf16_t)a, y = (bf16_t)b;
    return (uint32_t)__builtin_bit_cast(unsigned short, x)
         | ((uint32_t)__builtin_bit_cast(unsigned short, y) << 16);
}

// Bt swizzle: row stride 256 B; 16B chunk XOR by f(row) = ((row>>1)^(row>>2))&7.
// Reads (16 consecutive rows) and writes (rows 4q+d) both spread across all 8
// chunk slots -> near-optimal LDS phases on both sides.
__device__ __forceinline__ int bt_off(int row, int colbyte) {
    int f = ((row >> 1) ^ (row >> 2)) & 7;
    return row * 256 + (colbyte ^ (f << 4));
}

// ---- fused main ----
__global__ __launch_bounds__(512, 2)
void wtconv_mfma(const float* __restrict__ x,
                 const bf16_t* __restrict__ awp,
                 const float* __restrict__ lwall,
                 float* __restrict__ out)
{
    __shared__ __align__(16) float  lx[32][5][136];  // 87,040 B; borders stay 0
    __shared__ __align__(16) char   BtB[128 * 256];  // 32,768 B feats^T swizzled
    __shared__ __align__(16) float  lw[2][32][36];   //  9,216 B conv weights pingpong

    const int tid = threadIdx.x;
    const int nb = blockIdx.x;                 // XCD swizzle: XCD owns one batch
    const int m = (nb & 7) * 128 + (nb >> 3);
    const int b = m >> 7, i = m & 127;
    const int wave = tid >> 6, lane = tid & 63;
    const int wm = wave & 3, wn = wave >> 2;   // 4 M-waves x 2 N-waves
    const int lrow = lane & 15, lkh = lane >> 4;
    const float* xb = x + (size_t)b * CC * HH * WW;

    // zero all of lx once (pad cols 0,1,130,131 + OOB rows never reloaded)
    for (int e = tid; e < 32 * 5 * 136 / 4; e += 512)
        ((f32x4*)lx)[e] = (f32x4){0.f, 0.f, 0.f, 0.f};
    __syncthreads();   // zeros land before any global_load_lds

    f32x4 acc[8][4];
#pragma unroll
    for (int a = 0; a < 8; ++a)
#pragma unroll
        for (int c = 0; c < 4; ++c) acc[a][c] = (f32x4){0.f, 0.f, 0.f, 0.f};

    // ---- async issue of x window for chan-block cb (320 chunks of 64 lanes) ----
    auto issue_lx = [&](int cb) {
        const int q4 = cb >> 2;                 // quadrant (uniform in cb)
        const int qy = q4 >> 1, qx = q4 & 1;
        const int bcb = (cb & 3) * 32;          // base channel
#pragma unroll 1
        for (int t = 0; t < 40; ++t) {
            int q = wave * 40 + t;
            int chan = (q * 6554) >> 16;        // q/10
            int rem = q - chan * 10;
            int r = rem >> 1, h = rem & 1;
            int ri = i + r - 2;
            if ((unsigned)ri < 128u) {
                const float* src = xb + (size_t)(bcb + chan) * (HH * WW)
                                 + (2 * ri + qy) * WW + 2 * (h * 64 + lane) + qx;
                gload4(src, &lx[chan][r][2 + h * 64]);
            }
        }
    };
    auto issue_lw = [&](int cb, int buf) {
        const float* src = lwall + cb * (32 * 36);
        float* dst = &lw[buf][0][0];
#pragma unroll 1
        for (int t = wave; t < 18; t += 8)
            gload4(src + t * 64 + lane, dst + t * 64);
    };

    issue_lw(0, 0);
    issue_lx(0);

    const int pxq = tid & 31, e = tid >> 5;    // px-quad, chan-pair {2e, 2e+1}
    const int px0 = pxq * 4;

#pragma unroll 1
    for (int cb = 0; cb < 16; ++cb) {
        __syncthreads();   // drains vmcnt(0): lx(cb)/lw ready; fences Bt after GEMM(cb-1)

        // ---- depthwise convs: thread = (px-quad, chan-pair {2e,2e+1}) ----
        const int buf = cb & 1;
        float fw5[2][4], fw3[2][4], fw1[2][4];
#pragma unroll
        for (int cc = 0; cc < 2; ++cc) {
            const int chan = 2 * e + cc;
            f32x4 wv[9];
#pragma unroll
            for (int t = 0; t < 9; ++t)
                wv[t] = *(const f32x4*)&lw[buf][chan][t * 4];
#define WT(idx) (wv[(idx) >> 2][(idx) & 3])
            float f5[4] = {0.f, 0.f, 0.f, 0.f}, f3[4] = {0.f, 0.f, 0.f, 0.f}, f1[4];
#pragma unroll
            for (int r = 0; r < 5; ++r) {
                f32x4 a = *(const f32x4*)&lx[chan][r][px0];
                f32x4 bv = *(const f32x4*)&lx[chan][r][px0 + 4];
                float col[8] = {a[0], a[1], a[2], a[3], bv[0], bv[1], bv[2], bv[3]};
#pragma unroll
                for (int d = 0; d < 4; ++d)
#pragma unroll
                    for (int v = 0; v < 5; ++v)
                        f5[d] += WT(r * 5 + v) * col[d + v];
                if (r >= 1 && r <= 3) {
#pragma unroll
                    for (int d = 0; d < 4; ++d)
#pragma unroll
                        for (int v = 0; v < 3; ++v)
                            f3[d] += WT(25 + (r - 1) * 3 + v) * col[d + 1 + v];
                }
                if (r == 2) {
#pragma unroll
                    for (int d = 0; d < 4; ++d)
                        f1[d] = WT(34) * col[d + 2];
                }
            }
#undef WT
#pragma unroll
            for (int d = 0; d < 4; ++d) {
                fw5[cc][d] = f5[d]; fw3[cc][d] = f3[d]; fw1[cc][d] = f1[d];
            }
        }
        // packed chan-pair b32 writes into swizzled Bt (k = g*32 + 2e (+1))
#pragma unroll
        for (int d = 0; d < 4; ++d) {
            const int row = px0 + d;
            const int cbyte = e * 4;
            *(uint32_t*)&BtB[bt_off(row, cbyte)]        = pk_bf16(fw1[0][d], fw1[1][d]);
            *(uint32_t*)&BtB[bt_off(row, 64 + cbyte)]   = pk_bf16(fw3[0][d], fw3[1][d]);
            *(uint32_t*)&BtB[bt_off(row, 128 + cbyte)]  = pk_bf16(fw5[0][d], fw5[1][d]);
        }
        __syncthreads();   // Bt(cb) ready; all waves done reading lx(cb)

        // ---- prefetch next tile (latency hidden under GEMM) ----
        if (cb < 15) { issue_lw(cb + 1, (cb + 1) & 1); issue_lx(cb + 1); }

        // ---- GEMM: B from swizzled LDS, A direct from L2-resident awp ----
#pragma unroll 1
        for (int g = 0; g < 3; ++g) {
            bf16x8 bfrag[4];
#pragma unroll
            for (int nf = 0; nf < 4; ++nf) {
                const int row = wn * 64 + nf * 16 + lrow;
                bfrag[nf] = *(const bf16x8*)&BtB[bt_off(row, g * 64 + lkh * 16)];
            }
            const bf16_t* abase = awp + (size_t)(g * 16 + cb) * (512 * 32);
#pragma unroll
            for (int mf = 0; mf < 8; ++mf) {
                const int o = wm * 128 + mf * 16 + lrow;
                bf16x8 af = *(const bf16x8*)(abase + o * 32 + lkh * 8);
#pragma unroll
                for (int nf = 0; nf < 4; ++nf)
                    acc[mf][nf] = __builtin_amdgcn_mfma_f32_16x16x32_bf16(
                        af, bfrag[nf], acc[mf][nf], 0, 0, 0);
            }
        }
    }

    // ---- IDWT scatter epilogue: o-quadrant == wm ----
    const int oy = 2 * i + (wm >> 1);
    const int ox = wm & 1;
#pragma unroll
    for (int mf = 0; mf < 8; ++mf)
#pragma unroll
        for (int nf = 0; nf < 4; ++nf)
#pragma unroll
            for (int r = 0; r < 4; ++r) {
                int o  = wm * 128 + mf * 16 + lkh * 4 + r;
                int px = wn * 64 + nf * 16 + lrow;
                int bco = o & 127;
                out[((size_t)(b * CC + bco) * HH + oy) * WW + 2 * px + ox]
                    = acc[mf][nf][r];
            }
}

extern "C" void kernel_launch(void* const* d_in, const int* in_sizes, int n_in,
                              void* d_out, int out_size, void* d_ws, size_t ws_size,
                              hipStream_t stream) {
    const float* x  = (const float*)d_in[0];
    const float* w1 = (const float*)d_in[1];
    const float* w3 = (const float*)d_in[2];
    const float* w5 = (const float*)d_in[3];
    const float* wp = (const float*)d_in[4];
    float* out = (float*)d_out;
    bf16_t* awp  = (bf16_t*)d_ws;                                  // 1.50 MB
    float* lwall = (float*)((char*)d_ws + (size_t)AWP_ELEMS * 2);  // 72 KB

    int prep_total = AWP_ELEMS + 512 * 36;
    hipLaunchKernelGGL(prep, dim3((prep_total + 255) / 256), dim3(256), 0, stream,
                       wp, w1, w3, w5, awp, lwall);
    hipLaunchKernelGGL(wtconv_mfma, dim3(1024), dim3(512), 0, stream,
                       x, awp, lwall, out);
}

// Round 6
// 536.830 us; speedup vs baseline: 15.2136x; 1.1833x over previous
//
#include <hip/hip_runtime.h>
#include <hip/hip_bf16.h>
#include <stdint.h>

typedef __bf16 bf16_t;
typedef __bf16 bf16x8 __attribute__((ext_vector_type(8)));
typedef float f32x4 __attribute__((ext_vector_type(4)));

constexpr int CC = 128, HH = 256, WW = 256;
constexpr int C4 = 512, K12 = 1536;
constexpr int AWP_ELEMS = 786432;        // 512 o x 1536 k bf16, tiled
constexpr int LW2_ELEMS = 512 * 40;      // conv weights [c4][5][8] f32

// ---- prep: pack w_proj -> bf16 tiled [g*16+cb][o][32k]; conv w -> [c4][5][8] ----
// row r slots: [0..4] = w5 row r; [5..7] = w3 row r-1 (rows 1..3); [0][5] = w1.
__global__ __launch_bounds__(256)
void prep(const float* __restrict__ wp, const float* __restrict__ w1,
          const float* __restrict__ w3, const float* __restrict__ w5,
          bf16_t* __restrict__ awp, float* __restrict__ lw2g)
{
    int t = blockIdx.x * 256 + threadIdx.x;
    if (t < AWP_ELEMS) {
        int kk = t & 31, o = (t >> 5) & 511, t2 = t >> 14;
        int g = t2 >> 4, cb = t2 & 15;
        awp[t] = (bf16_t)wp[o * K12 + g * C4 + cb * 32 + kk];
        return;
    }
    int u = t - AWP_ELEMS;
    if (u < LW2_ELEMS) {
        int c4 = u / 40, j = u - c4 * 40;
        int r = j >> 3, v = j & 7;
        float val = 0.f;
        if (v < 5)                 val = w5[c4 * 25 + r * 5 + v];
        else if (r >= 1 && r <= 3) val = w3[c4 * 9 + (r - 1) * 3 + (v - 5)];
        else if (r == 0 && v == 5) val = w1[c4];
        lw2g[u] = val;
    }
}

__device__ __forceinline__ void gload4(const float* g, float* l) {
    __builtin_amdgcn_global_load_lds(
        (const __attribute__((address_space(1))) uint32_t*)g,
        (__attribute__((address_space(3))) uint32_t*)l, 4, 0, 0);
}

// Bt swizzle: row stride 256 B; 16B chunk XOR by f(row) = ((row>>1)^(row>>2))&7.
// b128 reads over 16 consecutive rows -> uniform 8 lanes/chunk-slot (free);
// b16 writes (rows 4p+d) ~4-way.
__device__ __forceinline__ int bt_off(int row, int colbyte) {
    int f = ((row >> 1) ^ (row >> 2)) & 7;
    return row * 256 + (colbyte ^ (f << 4));
}

__device__ __forceinline__ uint16_t b16bits(float v) {
    return __builtin_bit_cast(uint16_t, (bf16_t)v);
}

// ---- fused main: 1024 threads, 16 waves (4/SIMD), 1 block/CU ----
__global__ __launch_bounds__(1024, 4)
void wtconv_mfma(const float* __restrict__ x,
                 const bf16_t* __restrict__ awp,
                 const float* __restrict__ lw2g,
                 float* __restrict__ out)
{
    __shared__ __align__(16) float lx[32][5][136];   // 87,040 B; borders stay 0
    __shared__ __align__(16) char  BtB[128 * 256];   // 32,768 B feats^T swizzled
    __shared__ __align__(16) float lw2s[2][1280];    // 10,240 B conv w pingpong

    const int tid = threadIdx.x;
    const int lane = tid & 63;
    const int wid = __builtin_amdgcn_readfirstlane(tid >> 6);  // scalar wave id
    const int nb = blockIdx.x;                 // XCD swizzle: XCD owns one batch
    const int m = (nb & 7) * 128 + (nb >> 3);
    const int b = m >> 7, i = m & 127;
    const int wm = wid & 7, wn = wid >> 3;     // 8 M-waves x 2 N-waves
    const int lrow = lane & 15, lkh = lane >> 4;
    const float* xb = x + (size_t)b * CC * HH * WW;

    // zero lx once (pad cols 0,1,130,131 + OOB rows never reloaded)
    for (int e = tid; e < 32 * 5 * 136 / 4; e += 1024)
        ((f32x4*)lx)[e] = (f32x4){0.f, 0.f, 0.f, 0.f};
    __syncthreads();

    f32x4 acc[4][4];
#pragma unroll
    for (int a = 0; a < 4; ++a)
#pragma unroll
        for (int c = 0; c < 4; ++c) acc[a][c] = (f32x4){0.f, 0.f, 0.f, 0.f};

    // ---- fully-scalar chunk staging: wid/cl/r/h compile-time or SGPR ----
    auto issue_lx = [&](int cb) {
        const int q4 = cb >> 2;
        const int qy = q4 >> 1, qx = q4 & 1;
        const int bcb = (cb & 3) * 32;
#pragma unroll
        for (int cl = 0; cl < 2; ++cl) {
            const int chan = wid * 2 + cl;
#pragma unroll
            for (int r = 0; r < 5; ++r) {
                const int ri = i + r - 2;
                if ((unsigned)ri < 128u) {
#pragma unroll
                    for (int h = 0; h < 2; ++h) {
                        const float* s = xb + (((size_t)(bcb + chan)) << 16)
                                       + (2 * ri + qy) * WW + qx + h * 128;
                        gload4(s + 2 * lane, &lx[chan][r][2 + h * 64]);
                    }
                }
            }
        }
    };
    auto issue_lw = [&](int cb, int buf) {
        const float* src = lw2g + cb * 1280;
        float* dst = lw2s[buf];
#pragma unroll 1
        for (int t = wid; t < 20; t += 16)
            gload4(src + t * 64 + lane, dst + t * 64);
    };

    issue_lw(0, 0);
    issue_lx(0);

    const int pxq = tid & 31;                // px quad
    const int chan = (tid >> 5) & 31;        // 1 channel per thread
    const int px0 = pxq * 4;

#pragma unroll 1
    for (int cb = 0; cb < 16; ++cb) {
        __syncthreads();   // vmcnt(0) drain: lx(cb)/lw ready; fences Bt after GEMM(cb-1)

        // ---- depthwise convs: thread = (px-quad, chan) ----
        const int buf = cb & 1;
        const float* wrow = &lw2s[buf][chan * 40];
        float f5[4] = {0.f,0.f,0.f,0.f}, f3[4] = {0.f,0.f,0.f,0.f}, f1[4];
        float w1v = 0.f;
#pragma unroll
        for (int r = 0; r < 5; ++r) {
            f32x4 wA = *(const f32x4*)(wrow + r * 8);
            f32x4 wB = *(const f32x4*)(wrow + r * 8 + 4);
            f32x4 a  = *(const f32x4*)&lx[chan][r][px0];
            f32x4 bv = *(const f32x4*)&lx[chan][r][px0 + 4];
            float col[8] = {a[0],a[1],a[2],a[3],bv[0],bv[1],bv[2],bv[3]};
            if (r == 0) w1v = wB[1];
#pragma unroll
            for (int d = 0; d < 4; ++d)
                f5[d] += wA[0]*col[d] + wA[1]*col[d+1] + wA[2]*col[d+2]
                       + wA[3]*col[d+3] + wB[0]*col[d+4];
            if (r >= 1 && r <= 3) {
#pragma unroll
                for (int d = 0; d < 4; ++d)
                    f3[d] += wB[1]*col[d+1] + wB[2]*col[d+2] + wB[3]*col[d+3];
            }
            if (r == 2) {
#pragma unroll
                for (int d = 0; d < 4; ++d) f1[d] = w1v * col[d + 2];
            }
        }
#pragma unroll
        for (int d = 0; d < 4; ++d) {
            const int row = px0 + d;
            const int cby = chan * 2;
            *(uint16_t*)&BtB[bt_off(row, cby)]       = b16bits(f1[d]);
            *(uint16_t*)&BtB[bt_off(row, 64 + cby)]  = b16bits(f3[d]);
            *(uint16_t*)&BtB[bt_off(row, 128 + cby)] = b16bits(f5[d]);
        }
        __syncthreads();   // Bt(cb) ready; all waves done reading lx(cb)

        // ---- prefetch next tile (latency hidden under GEMM) ----
        if (cb < 15) { issue_lw(cb + 1, (cb + 1) & 1); issue_lx(cb + 1); }

        // ---- GEMM: B from swizzled LDS, A direct from L2-resident awp ----
#pragma unroll 1
        for (int g = 0; g < 3; ++g) {
            bf16x8 bfrag[4];
#pragma unroll
            for (int nf = 0; nf < 4; ++nf) {
                const int row = wn * 64 + nf * 16 + lrow;
                bfrag[nf] = *(const bf16x8*)&BtB[bt_off(row, g * 64 + lkh * 16)];
            }
            const bf16_t* abase = awp + (size_t)(g * 16 + cb) * (512 * 32);
#pragma unroll
            for (int mf = 0; mf < 4; ++mf) {
                const int o = wm * 64 + mf * 16 + lrow;
                bf16x8 af = *(const bf16x8*)(abase + o * 32 + lkh * 8);
#pragma unroll
                for (int nf = 0; nf < 4; ++nf)
                    acc[mf][nf] = __builtin_amdgcn_mfma_f32_16x16x32_bf16(
                        af, bfrag[nf], acc[mf][nf], 0, 0, 0);
            }
        }
    }

    // ---- IDWT scatter epilogue: quadrant = wm>>1 ----
    const int oy = 2 * i + (wm >> 2);
    const int ox = (wm >> 1) & 1;
#pragma unroll
    for (int mf = 0; mf < 4; ++mf)
#pragma unroll
        for (int nf = 0; nf < 4; ++nf)
#pragma unroll
            for (int r = 0; r < 4; ++r) {
                const int bco = (wm & 1) * 64 + mf * 16 + lkh * 4 + r;
                const int px  = wn * 64 + nf * 16 + lrow;
                out[((size_t)(b * CC + bco) * HH + oy) * WW + 2 * px + ox]
                    = acc[mf][nf][r];
            }
}

extern "C" void kernel_launch(void* const* d_in, const int* in_sizes, int n_in,
                              void* d_out, int out_size, void* d_ws, size_t ws_size,
                              hipStream_t stream) {
    const float* x  = (const float*)d_in[0];
    const float* w1 = (const float*)d_in[1];
    const float* w3 = (const float*)d_in[2];
    const float* w5 = (const float*)d_in[3];
    const float* wp = (const float*)d_in[4];
    float* out = (float*)d_out;
    bf16_t* awp = (bf16_t*)d_ws;                                   // 1.50 MB
    float* lw2g = (float*)((char*)d_ws + (size_t)AWP_ELEMS * 2);   // 80 KB

    int prep_total = AWP_ELEMS + LW2_ELEMS;
    hipLaunchKernelGGL(prep, dim3((prep_total + 255) / 256), dim3(256), 0, stream,
                       wp, w1, w3, w5, awp, lw2g);
    hipLaunchKernelGGL(wtconv_mfma, dim3(1024), dim3(1024), 0, stream,
                       x, awp, lw2g, out);
}